// Round 1
// baseline (332.445 us; speedup 1.0000x reference)
//
#include <hip/hip_runtime.h>
#include <stdint.h>

// Problem constants (B=4, T=1024, D=512, H=8, hd=64)
#define BB 4
#define TT 1024
#define DD 512
#define HH 8
#define HDIM 64

typedef short bf16x8 __attribute__((ext_vector_type(8)));
typedef float f32x4 __attribute__((ext_vector_type(4)));

__device__ __forceinline__ unsigned short f2bf(float f) {
  union { float f; unsigned int u; } v;
  v.f = f;
  unsigned int u = v.u;
  u = (u + 0x7fffu + ((u >> 16) & 1u)) >> 16;  // RNE
  return (unsigned short)u;
}

__device__ __forceinline__ float bf2f(unsigned short h) {
  union { unsigned int u; float f; } v;
  v.u = ((unsigned int)h) << 16;
  return v.f;
}

// ---------------------------------------------------------------------------
// Kernel 1: prep — x -> bf16, 7 weights -> transposed bf16 (Wt[n][k] = W[k][n])
// blocks 0..447: weight transpose tiles; blocks 448..511: x conversion
// ---------------------------------------------------------------------------
__global__ __launch_bounds__(256) void prep_kernel(
    const float* __restrict__ x,
    const float* __restrict__ Wq, const float* __restrict__ Wk, const float* __restrict__ Wv,
    const float* __restrict__ Wfh, const float* __restrict__ Wfg,
    const float* __restrict__ Wrh, const float* __restrict__ Wrg,
    unsigned short* __restrict__ xb, unsigned short* __restrict__ wt) {
  int bid = blockIdx.x;
  int tid = threadIdx.x;
  if (bid < 448) {
    __shared__ float tile[64][65];
    int mat = bid >> 6;          // 0..6
    int t = bid & 63;            // 64 tiles of 64x64 in a 512x512 matrix
    int tr = (t >> 3) * 64, tc = (t & 7) * 64;
    const float* W = (mat == 0) ? Wq : (mat == 1) ? Wk : (mat == 2) ? Wv
                   : (mat == 3) ? Wfh : (mat == 4) ? Wfg : (mat == 5) ? Wrh : Wrg;
    unsigned short* Wt = wt + (size_t)mat * 512 * 512;
    for (int rep = 0; rep < 16; rep++) {
      int idx = rep * 256 + tid;
      int r = idx >> 6, c = idx & 63;
      tile[r][c] = W[(tr + r) * 512 + tc + c];
    }
    __syncthreads();
    for (int rep = 0; rep < 16; rep++) {
      int idx = rep * 256 + tid;
      int r = idx >> 6, c = idx & 63;
      Wt[(tc + r) * 512 + tr + c] = f2bf(tile[c][r]);  // Wt[n][k] = W[k][n]
    }
  } else {
    int blk = bid - 448;  // 64 blocks, 4096*512/4 = 524288 float4 total
    const float4* xi = (const float4*)x;
    for (int rep = 0; rep < 32; rep++) {
      int i = blk * 256 + tid + rep * 16384;
      float4 v = xi[i];
      unsigned int lo = (unsigned int)f2bf(v.x) | ((unsigned int)f2bf(v.y) << 16);
      unsigned int hi = (unsigned int)f2bf(v.z) | ((unsigned int)f2bf(v.w) << 16);
      uint2 u; u.x = lo; u.y = hi;
      *(uint2*)&xb[(size_t)i * 4] = u;
    }
  }
}

// ---------------------------------------------------------------------------
// Kernel 2: QKV projection. out rows 4096, cols 512, K=512, 3 outputs.
// Q gets softmax scale (1/8) folded in. V written transposed:
// Vtb[(b*8+h)*64+d][t] for PV A-fragments.
// grid (64 mtiles, 8 ntiles), 256 threads (4 waves, 16 rows each).
// ---------------------------------------------------------------------------
__global__ __launch_bounds__(256) void qkv_kernel(
    const unsigned short* __restrict__ xb,
    const unsigned short* __restrict__ wtq, const unsigned short* __restrict__ wtk,
    const unsigned short* __restrict__ wtv,
    const float* __restrict__ bq, const float* __restrict__ bk, const float* __restrict__ bv,
    unsigned short* __restrict__ Qb, unsigned short* __restrict__ Kb,
    unsigned short* __restrict__ Vtb) {
  int mt = blockIdx.x;
  int nb = blockIdx.y;
  int w = threadIdx.x >> 6;
  int lane = threadIdx.x & 63;
  int c = lane & 15, quad = lane >> 4;
  int row_a = mt * 64 + w * 16 + c;

  f32x4 aq[4], ak[4], av[4];
  f32x4 z4 = {0.f, 0.f, 0.f, 0.f};
  for (int i = 0; i < 4; i++) { aq[i] = z4; ak[i] = z4; av[i] = z4; }

  for (int kc = 0; kc < 512; kc += 32) {
    bf16x8 xa = *(const bf16x8*)&xb[(size_t)row_a * 512 + kc + quad * 8];
    for (int nt = 0; nt < 4; nt++) {
      int n = nb * 64 + nt * 16 + c;
      bf16x8 fq = *(const bf16x8*)&wtq[(size_t)n * 512 + kc + quad * 8];
      bf16x8 fk = *(const bf16x8*)&wtk[(size_t)n * 512 + kc + quad * 8];
      bf16x8 fv = *(const bf16x8*)&wtv[(size_t)n * 512 + kc + quad * 8];
      aq[nt] = __builtin_amdgcn_mfma_f32_16x16x32_bf16(xa, fq, aq[nt], 0, 0, 0);
      ak[nt] = __builtin_amdgcn_mfma_f32_16x16x32_bf16(xa, fk, ak[nt], 0, 0, 0);
      av[nt] = __builtin_amdgcn_mfma_f32_16x16x32_bf16(xa, fv, av[nt], 0, 0, 0);
    }
  }

  for (int nt = 0; nt < 4; nt++) {
    int n = nb * 64 + nt * 16 + c;
    float biasq = bq[n], biask = bk[n], biasv = bv[n];
    int h = n >> 6, d = n & 63;
    unsigned short vp[4];
    for (int r = 0; r < 4; r++) {
      int t = mt * 64 + w * 16 + quad * 4 + r;
      Qb[(size_t)t * 512 + n] = f2bf((aq[nt][r] + biasq) * 0.125f);  // fold scale
      Kb[(size_t)t * 512 + n] = f2bf(ak[nt][r] + biask);
      vp[r] = f2bf(av[nt][r] + biasv);
    }
    int t0 = mt * 64 + w * 16 + quad * 4;
    int b = t0 >> 10;
    int tb = t0 & 1023;
    unsigned int lo = (unsigned int)vp[0] | ((unsigned int)vp[1] << 16);
    unsigned int hi = (unsigned int)vp[2] | ((unsigned int)vp[3] << 16);
    uint2 u; u.x = lo; u.y = hi;
    *(uint2*)&Vtb[((size_t)(b * 8 + h) * 64 + d) * 1024 + tb] = u;
  }
}

// ---------------------------------------------------------------------------
// Kernel 3: fused complementary attention.
// grid (64 qtiles, 4 batches), 512 threads = 8 waves, wave = head.
// Pass 1: Z_h[q] = sum_k exp(s). Pass 2 per 32-k tile:
//   A: recompute S, a = exp(s)/Z -> A_lds
//   B: per (q,k): R_f across heads -> masks -> ef/er bf16 -> P_lds
//   C: PV MFMA (unnormalized), Zf/Zr accumulated from P fragments
// Epilogue: divide, store T_f/T_r bf16.
// ---------------------------------------------------------------------------
__global__ __launch_bounds__(512) void attn_kernel(
    const unsigned short* __restrict__ Qb, const unsigned short* __restrict__ Kb,
    const unsigned short* __restrict__ Vtb,
    const float* __restrict__ conv_w, const float* __restrict__ conv_b,
    unsigned short* __restrict__ Tfb, unsigned short* __restrict__ Trb) {
  int qt = blockIdx.x;
  int b = blockIdx.y;
  int h = threadIdx.x >> 6;
  int lane = threadIdx.x & 63;
  int c = lane & 15, quad = lane >> 4;
  int q0 = qt * 16;

  __shared__ float Zl[8][16];
  __shared__ float Al[8][16][32];
  __shared__ __attribute__((aligned(16))) unsigned short Pfl[8][16][32];
  __shared__ __attribute__((aligned(16))) unsigned short Prl[8][16][32];

  // Q A-fragments for this head (kept in regs for both passes)
  size_t qrow = (size_t)(b * 1024 + q0 + c) * 512 + h * 64;
  bf16x8 aq0 = *(const bf16x8*)&Qb[qrow + 0 + quad * 8];
  bf16x8 aq1 = *(const bf16x8*)&Qb[qrow + 32 + quad * 8];

  // ---- pass 1: row sums Z (scores are small; no max subtraction needed) ----
  float zp[4] = {0.f, 0.f, 0.f, 0.f};
  f32x4 z4 = {0.f, 0.f, 0.f, 0.f};
  for (int kt = 0; kt < 32; kt++) {
    int k0 = kt * 32;
    for (int sub = 0; sub < 2; sub++) {
      size_t krow = (size_t)(b * 1024 + k0 + sub * 16 + c) * 512 + h * 64;
      bf16x8 bk0 = *(const bf16x8*)&Kb[krow + 0 + quad * 8];
      bf16x8 bk1 = *(const bf16x8*)&Kb[krow + 32 + quad * 8];
      f32x4 s = z4;
      s = __builtin_amdgcn_mfma_f32_16x16x32_bf16(aq0, bk0, s, 0, 0, 0);
      s = __builtin_amdgcn_mfma_f32_16x16x32_bf16(aq1, bk1, s, 0, 0, 0);
      zp[0] += __expf(s[0]); zp[1] += __expf(s[1]);
      zp[2] += __expf(s[2]); zp[3] += __expf(s[3]);
    }
  }
#pragma unroll
  for (int r = 0; r < 4; r++) {
    float z = zp[r];
    z += __shfl_xor(z, 1); z += __shfl_xor(z, 2);
    z += __shfl_xor(z, 4); z += __shfl_xor(z, 8);
    if (c == r) Zl[h][quad * 4 + r] = z;
  }
  __syncthreads();
  float invZ[4];
#pragma unroll
  for (int r = 0; r < 4; r++) invZ[r] = 1.0f / Zl[h][quad * 4 + r];

  float cw[8];
#pragma unroll
  for (int i = 0; i < 8; i++) cw[i] = conv_w[i];
  float cb = conv_b[0];

  f32x4 accf[4], accr[4];
  for (int i = 0; i < 4; i++) { accf[i] = z4; accr[i] = z4; }
  float zf = 0.f, zr = 0.f;

  int qB = threadIdx.x >> 5;  // 0..15
  int kB = threadIdx.x & 31;  // 0..31

  // ---- pass 2 ----
  for (int kt = 0; kt < 32; kt++) {
    int k0 = kt * 32;
    // phase A: S recompute -> a = A_t values into LDS
    for (int sub = 0; sub < 2; sub++) {
      size_t krow = (size_t)(b * 1024 + k0 + sub * 16 + c) * 512 + h * 64;
      bf16x8 bk0 = *(const bf16x8*)&Kb[krow + 0 + quad * 8];
      bf16x8 bk1 = *(const bf16x8*)&Kb[krow + 32 + quad * 8];
      f32x4 s = z4;
      s = __builtin_amdgcn_mfma_f32_16x16x32_bf16(aq0, bk0, s, 0, 0, 0);
      s = __builtin_amdgcn_mfma_f32_16x16x32_bf16(aq1, bk1, s, 0, 0, 0);
#pragma unroll
      for (int r = 0; r < 4; r++)
        Al[h][quad * 4 + r][sub * 16 + c] = __expf(s[r]) * invZ[r];
    }
    __syncthreads();
    // phase B: masks (cross-head, in-lane) and P values
    {
      float av[8];
#pragma unroll
      for (int i = 0; i < 8; i++) av[i] = Al[i][qB][kB];
      float zc = cb;
#pragma unroll
      for (int i = 0; i < 8; i++) zc += cw[i] * av[i];
      float rf = 1.0f / (1.0f + __expf(-zc));
      bool mf = (rf <= 0.5f);
      bool mr = ((1.0f - rf) <= 0.5f);
#pragma unroll
      for (int i = 0; i < 8; i++) {
        float ea = __expf(av[i]);
        Pfl[i][qB][kB] = f2bf(mf ? ea : 1.0f);  // exp(a*M): masked -> exp(0)=1
        Prl[i][qB][kB] = f2bf(mr ? ea : 1.0f);
      }
    }
    __syncthreads();
    // phase C: PV MFMA + Zf/Zr from the very fragments fed to MFMA
    bf16x8 pf = *(const bf16x8*)&Pfl[h][c][quad * 8];
    bf16x8 pr = *(const bf16x8*)&Prl[h][c][quad * 8];
#pragma unroll
    for (int j = 0; j < 8; j++) {
      zf += bf2f((unsigned short)pf[j]);
      zr += bf2f((unsigned short)pr[j]);
    }
#pragma unroll
    for (int dm = 0; dm < 4; dm++) {
      bf16x8 vv = *(const bf16x8*)&Vtb[((size_t)(b * 8 + h) * 64 + dm * 16 + c) * 1024 + k0 + quad * 8];
      accf[dm] = __builtin_amdgcn_mfma_f32_16x16x32_bf16(vv, pf, accf[dm], 0, 0, 0);
      accr[dm] = __builtin_amdgcn_mfma_f32_16x16x32_bf16(vv, pr, accr[dm], 0, 0, 0);
    }
    // no barrier needed here: next phase A touches Al only (safe after B2),
    // and next phase B's P writes come after the next barrier.
  }

  // epilogue: normalize and store (lane's acc cols are q=c; rows are d)
  zf += __shfl_xor(zf, 16); zf += __shfl_xor(zf, 32);
  zr += __shfl_xor(zr, 16); zr += __shfl_xor(zr, 32);
  float izf = 1.0f / zf, izr = 1.0f / zr;
  size_t trow = (size_t)(b * 1024 + q0 + c) * 512 + h * 64;
#pragma unroll
  for (int dm = 0; dm < 4; dm++) {
    unsigned short p0 = f2bf(accf[dm][0] * izf), p1 = f2bf(accf[dm][1] * izf);
    unsigned short p2 = f2bf(accf[dm][2] * izf), p3 = f2bf(accf[dm][3] * izf);
    uint2 u;
    u.x = (unsigned int)p0 | ((unsigned int)p1 << 16);
    u.y = (unsigned int)p2 | ((unsigned int)p3 << 16);
    *(uint2*)&Tfb[trow + dm * 16 + quad * 4] = u;
    p0 = f2bf(accr[dm][0] * izr); p1 = f2bf(accr[dm][1] * izr);
    p2 = f2bf(accr[dm][2] * izr); p3 = f2bf(accr[dm][3] * izr);
    u.x = (unsigned int)p0 | ((unsigned int)p1 << 16);
    u.y = (unsigned int)p2 | ((unsigned int)p3 << 16);
    *(uint2*)&Trb[trow + dm * 16 + quad * 4] = u;
  }
}

// ---------------------------------------------------------------------------
// Kernel 4: fused output projections + gate combine.
// F_f = Tf@Wfh+bfh ; G_f = sigmoid(Tf@Wfg+bfg) ; F_r,G_r likewise from Tr.
// out = (F_f*e^Gf + F_r*e^Gr) / (e^Gf + e^Gr)   (2-way softmax gate)
// ---------------------------------------------------------------------------
__global__ __launch_bounds__(256) void final_kernel(
    const unsigned short* __restrict__ Tfb, const unsigned short* __restrict__ Trb,
    const unsigned short* __restrict__ wfh, const unsigned short* __restrict__ wfg,
    const unsigned short* __restrict__ wrh, const unsigned short* __restrict__ wrg,
    const float* __restrict__ bfh, const float* __restrict__ bfg,
    const float* __restrict__ brh, const float* __restrict__ brg,
    float* __restrict__ out) {
  int mt = blockIdx.x;
  int nb = blockIdx.y;
  int w = threadIdx.x >> 6;
  int lane = threadIdx.x & 63;
  int c = lane & 15, quad = lane >> 4;
  int row_a = mt * 64 + w * 16 + c;

  f32x4 aFh[4], aFg[4], aRh[4], aRg[4];
  f32x4 z4 = {0.f, 0.f, 0.f, 0.f};
  for (int i = 0; i < 4; i++) { aFh[i] = z4; aFg[i] = z4; aRh[i] = z4; aRg[i] = z4; }

  for (int kc = 0; kc < 512; kc += 32) {
    bf16x8 tf = *(const bf16x8*)&Tfb[(size_t)row_a * 512 + kc + quad * 8];
    bf16x8 tr = *(const bf16x8*)&Trb[(size_t)row_a * 512 + kc + quad * 8];
    for (int nt = 0; nt < 4; nt++) {
      int n = nb * 64 + nt * 16 + c;
      bf16x8 f0 = *(const bf16x8*)&wfh[(size_t)n * 512 + kc + quad * 8];
      bf16x8 f1 = *(const bf16x8*)&wfg[(size_t)n * 512 + kc + quad * 8];
      bf16x8 f2 = *(const bf16x8*)&wrh[(size_t)n * 512 + kc + quad * 8];
      bf16x8 f3 = *(const bf16x8*)&wrg[(size_t)n * 512 + kc + quad * 8];
      aFh[nt] = __builtin_amdgcn_mfma_f32_16x16x32_bf16(tf, f0, aFh[nt], 0, 0, 0);
      aFg[nt] = __builtin_amdgcn_mfma_f32_16x16x32_bf16(tf, f1, aFg[nt], 0, 0, 0);
      aRh[nt] = __builtin_amdgcn_mfma_f32_16x16x32_bf16(tr, f2, aRh[nt], 0, 0, 0);
      aRg[nt] = __builtin_amdgcn_mfma_f32_16x16x32_bf16(tr, f3, aRg[nt], 0, 0, 0);
    }
  }

  for (int nt = 0; nt < 4; nt++) {
    int n = nb * 64 + nt * 16 + c;
    float b0 = bfh[n], b1 = bfg[n], b2 = brh[n], b3 = brg[n];
#pragma unroll
    for (int r = 0; r < 4; r++) {
      int t = mt * 64 + w * 16 + quad * 4 + r;
      float Ff = aFh[nt][r] + b0;
      float Gf = 1.0f / (1.0f + __expf(-(aFg[nt][r] + b1)));
      float Fr = aRh[nt][r] + b2;
      float Gr = 1.0f / (1.0f + __expf(-(aRg[nt][r] + b3)));
      float ef = __expf(Gf), er = __expf(Gr);
      out[(size_t)t * 512 + n] = (Ff * ef + Fr * er) / (ef + er);
    }
  }
}

// ---------------------------------------------------------------------------
// Launch. Workspace layout (bytes):
//   0: xb 4MB | 4MB: Qb 4MB | 8MB: Kb 4MB | 12MB: Vtb 4MB
//   16MB: Tfb 4MB | 20MB: Trb 4MB | 24MB: 7x transposed bf16 weights (3.5MB)
// ---------------------------------------------------------------------------
extern "C" void kernel_launch(void* const* d_in, const int* in_sizes, int n_in,
                              void* d_out, int out_size, void* d_ws, size_t ws_size,
                              hipStream_t stream) {
  const float* x   = (const float*)d_in[0];
  const float* Wq  = (const float*)d_in[1];
  const float* bq  = (const float*)d_in[2];
  const float* Wk  = (const float*)d_in[3];
  const float* bk  = (const float*)d_in[4];
  const float* Wv  = (const float*)d_in[5];
  const float* bv  = (const float*)d_in[6];
  const float* cw  = (const float*)d_in[7];
  const float* cb  = (const float*)d_in[8];
  const float* Wfh = (const float*)d_in[9];
  const float* bfh = (const float*)d_in[10];
  const float* Wfg = (const float*)d_in[11];
  const float* bfg = (const float*)d_in[12];
  const float* Wrh = (const float*)d_in[13];
  const float* brh = (const float*)d_in[14];
  const float* Wrg = (const float*)d_in[15];
  const float* brg = (const float*)d_in[16];

  char* ws = (char*)d_ws;
  const size_t MB = 1024 * 1024;
  unsigned short* xb  = (unsigned short*)(ws + 0 * MB);
  unsigned short* Qb  = (unsigned short*)(ws + 4 * MB);
  unsigned short* Kb  = (unsigned short*)(ws + 8 * MB);
  unsigned short* Vtb = (unsigned short*)(ws + 12 * MB);
  unsigned short* Tfb = (unsigned short*)(ws + 16 * MB);
  unsigned short* Trb = (unsigned short*)(ws + 20 * MB);
  unsigned short* wt  = (unsigned short*)(ws + 24 * MB);
  const size_t WSZ = 512 * 512;

  prep_kernel<<<512, 256, 0, stream>>>(x, Wq, Wk, Wv, Wfh, Wfg, Wrh, Wrg, xb, wt);
  qkv_kernel<<<dim3(64, 8), 256, 0, stream>>>(xb, wt + 0 * WSZ, wt + 1 * WSZ, wt + 2 * WSZ,
                                              bq, bk, bv, Qb, Kb, Vtb);
  attn_kernel<<<dim3(64, 4), 512, 0, stream>>>(Qb, Kb, Vtb, cw, cb, Tfb, Trb);
  final_kernel<<<dim3(64, 8), 256, 0, stream>>>(Tfb, Trb, wt + 3 * WSZ, wt + 4 * WSZ,
                                                wt + 5 * WSZ, wt + 6 * WSZ,
                                                bfh, bfg, brh, brg, (float*)d_out);
}